// Round 4
// baseline (862.903 us; speedup 1.0000x reference)
//
#include <hip/hip_runtime.h>
#include <hip/hip_bf16.h>
#include <stdint.h>

// ---------- types ----------
typedef __attribute__((ext_vector_type(4))) float  f32x4;
typedef __attribute__((ext_vector_type(4))) float  fvec4;
typedef __attribute__((ext_vector_type(8))) short  bhalf8;   // 8 bf16 (raw bits)
typedef __attribute__((ext_vector_type(4))) short  bhalf4;

typedef const __attribute__((address_space(1))) void glb_void;
typedef __attribute__((address_space(3))) void lds_void;

#define HD 8192
#define KDIM 1024

__device__ __forceinline__ float bf2f(short s) {
  union { float f; uint32_t u; } cv; cv.u = ((uint32_t)(uint16_t)s) << 16; return cv.f;
}
__device__ __forceinline__ short f2bf(float f) {
  union { float f; uint32_t u; } cv; cv.f = f;
  uint32_t u = cv.u;
  uint32_t r = (u + 0x7FFFu + ((u >> 16) & 1u)) >> 16;  // RNE
  return (short)(uint16_t)r;
}

// ---------- 1) f32 -> bf16 convert ----------
__global__ void cvt_f32_bf16(const float* __restrict__ in, short* __restrict__ out, int n8) {
  int idx = blockIdx.x * blockDim.x + threadIdx.x;
  if (idx >= n8) return;
  fvec4 a = ((const fvec4*)in)[idx * 2 + 0];
  fvec4 b = ((const fvec4*)in)[idx * 2 + 1];
  bhalf8 o;
  o[0]=f2bf(a[0]); o[1]=f2bf(a[1]); o[2]=f2bf(a[2]); o[3]=f2bf(a[3]);
  o[4]=f2bf(b[0]); o[5]=f2bf(b[1]); o[6]=f2bf(b[2]); o[7]=f2bf(b[3]);
  ((bhalf8*)out)[idx] = o;
}

// ---------- 2) W[1024][8192] f32 -> WT[8192][1024] bf16 ----------
__global__ __launch_bounds__(256)
void transpose_w(const float* __restrict__ W, short* __restrict__ WT) {
  __shared__ float tile[64][65];
  const int bk = blockIdx.x;   // 16
  const int bn = blockIdx.y;   // 128
  const int t  = threadIdx.x;
  #pragma unroll
  for (int p = 0; p < 4; ++p) {
    int r = p * 16 + (t >> 4);
    int c = (t & 15) * 4;
    fvec4 v = *(const fvec4*)(W + (size_t)(bk * 64 + r) * HD + bn * 64 + c);
    tile[r][c+0] = v[0]; tile[r][c+1] = v[1]; tile[r][c+2] = v[2]; tile[r][c+3] = v[3];
  }
  __syncthreads();
  #pragma unroll
  for (int p = 0; p < 2; ++p) {
    int rr = p * 32 + (t >> 3);
    int cc = (t & 7) * 8;
    bhalf8 o;
    #pragma unroll
    for (int e = 0; e < 8; ++e) o[e] = f2bf(tile[cc + e][rr]);
    *(bhalf8*)(WT + (size_t)(bn * 64 + rr) * KDIM + bk * 64 + cc) = o;
  }
}

// =====================================================================
// 3a) 256x256 GEMM, 4-phase K-tile with 1-phase READ-AHEAD pipeline.
// Phase p: {issue ds_reads for phase p+1} || {stage tile t+2} || MFMA on
// operands read in phase p-1. One barrier per phase. vmcnt(0) only at
// P2-end (drains loads issued 3-4 phases earlier => effectively free).
// Stage-WAR audit (all airtight):
//   A(t+2)->buf[t&1] at P3: last A-read-issue of that region = a1(t)@P1,
//     drained before every wave's P2 MFMA; P3-start barrier follows => safe.
//   B(t+2)->buf[t&1] at P4: last B-read-issue = b1(t)@P2, drained before
//     P3 MFMA; P4-start barrier follows => safe.
//   Reads of tile t+1 (P3/P4, from buf^1): staged at P3/P4 of t-1;
//     vmcnt(0)@P2-end + P3 barrier => landed for all waves.
// =====================================================================
#define BAR()  __builtin_amdgcn_s_barrier()
#define PRIO1  __builtin_amdgcn_s_setprio(1)
#define PRIO0  __builtin_amdgcn_s_setprio(0)

// LDS tile: [256 rows][64 k] bf16, 128B rows (8 slots of 16B).
// Swizzle: slot' = slot ^ (row&7)  (read side + pre-swizzled global source).
#define READ_A(DST, BUF, ROFF)                                                   \
  _Pragma("unroll") for (int mi = 0; mi < 4; ++mi)                               \
  _Pragma("unroll") for (int ks = 0; ks < 2; ++ks) {                             \
    int r_ = arow + (ROFF) + mi * 16;                                            \
    DST[mi][ks] = *(const bhalf8*)(smem + (BUF)*32768 + r_*64 +                  \
                                   (((ks*4 + kq) ^ (r_ & 7)) * 8)); }
#define READ_B(DST, BUF, ROFF)                                                   \
  _Pragma("unroll") for (int ni = 0; ni < 2; ++ni)                               \
  _Pragma("unroll") for (int ks = 0; ks < 2; ++ks) {                             \
    int r_ = brow + (ROFF) + ni * 16;                                            \
    DST[ni][ks] = *(const bhalf8*)(smem + (BUF)*32768 + 16384 + r_*64 +          \
                                   (((ks*4 + kq) ^ (r_ & 7)) * 8)); }
// Stage one half-tile (128 rows x 64 k = 16KB): 2 x 1KB loads per wave.
// LDS linear dest; global k pre-swizzled by (lane>>3) = row&7.
#define STAGE_A(BUF, H, KT)                                                      \
  _Pragma("unroll") for (int L_ = 0; L_ < 2; ++L_) {                             \
    __builtin_amdgcn_global_load_lds(                                            \
      (glb_void*)(Ag + (size_t)((H)*128 + (w*2 + L_)*8) * 1024 + (KT)),          \
      (lds_void*)((char*)smem + (BUF)*65536 + (H)*16384 + (w*2 + L_)*1024),      \
      16, 0, 0); }
#define STAGE_B(BUF, H, KT)                                                      \
  _Pragma("unroll") for (int L_ = 0; L_ < 2; ++L_) {                             \
    __builtin_amdgcn_global_load_lds(                                            \
      (glb_void*)(Bg + (size_t)((H)*128 + (w*2 + L_)*8) * 1024 + (KT)),          \
      (lds_void*)((char*)smem + (BUF)*65536 + 32768 + (H)*16384 + (w*2+L_)*1024),\
      16, 0, 0); }
#define MFMA_Q(MO, NO, AFR, BFR)                                                 \
  _Pragma("unroll") for (int mi = 0; mi < 4; ++mi)                               \
  _Pragma("unroll") for (int ni = 0; ni < 2; ++ni)                               \
  _Pragma("unroll") for (int ks = 0; ks < 2; ++ks)                               \
    acc[(MO)+mi][(NO)+ni] = __builtin_amdgcn_mfma_f32_16x16x32_bf16(             \
        AFR[mi][ks], BFR[ni][ks], acc[(MO)+mi][(NO)+ni], 0, 0, 0);

// One K-tile t (buffer B=t&1). DOST: stage tile t+2. DORD: read tile t+1 frags.
#define KT2(B, DOST, DORD, KA) do {                                              \
  /* P1 */                                                                       \
  BAR();                                                                         \
  READ_A(a1, B, 64);                                                             \
  PRIO1; MFMA_Q(0, 0, a0, b0); PRIO0;                                            \
  /* P2 */                                                                       \
  BAR();                                                                         \
  READ_B(b1, B, 32);                                                             \
  PRIO1; MFMA_Q(4, 0, a1, b0); PRIO0;                                            \
  asm volatile("s_waitcnt vmcnt(0)" ::: "memory");                               \
  /* P3 */                                                                       \
  BAR();                                                                         \
  if (DOST) { STAGE_A(B, 0, KA); STAGE_A(B, 1, KA); }                            \
  if (DORD) { READ_B(b0, (B)^1, 0); }                                            \
  PRIO1; MFMA_Q(0, 2, a0, b1); PRIO0;                                            \
  /* P4 */                                                                       \
  BAR();                                                                         \
  if (DOST) { STAGE_B(B, 0, KA); STAGE_B(B, 1, KA); }                            \
  if (DORD) { READ_A(a0, (B)^1, 0); }                                            \
  PRIO1; MFMA_Q(4, 2, a1, b1); PRIO0;                                            \
} while (0)

template <bool TRANSPOSED>
__global__ __launch_bounds__(512, 2)
void gemm256(const short* __restrict__ A, const short* __restrict__ BT,
             const float* __restrict__ bias, short* __restrict__ C) {
  __shared__ alignas(16) short smem[65536];   // 128 KiB
  const int t    = threadIdx.x;
  const int lane = t & 63;
  const int w    = t >> 6;
  const int wr   = w >> 2, wc = w & 3;        // 2M x 4N waves
  const int kq   = lane >> 4;

  // L2-resident swizzle: XCD x (= id&7) owns 4 fixed bn columns (2 MB of B,
  // resident in its 4 MB L2); A panels reused 4x back-to-back.
  // grid = gm*32, gm = CB*4; blocks/XCD = grid/8 = gm*4.
  const int x  = blockIdx.x & 7;
  const int s  = blockIdx.x >> 3;
  const int bm = s >> 2;
  const int bn = x * 4 + (s & 3);

  const int srow = lane >> 3;
  const int gk   = ((lane & 7) ^ srow) * 8;
  const short* Ag = A  + (size_t)(bm * 256 + srow) * 1024 + gk;
  const short* Bg = BT + (size_t)(bn * 256 + srow) * 1024 + gk;

  const int arow = wr * 128 + (lane & 15);
  const int brow = wc * 64  + (lane & 15);

  f32x4 acc[8][4];
  #pragma unroll
  for (int i = 0; i < 8; ++i)
    #pragma unroll
    for (int j = 0; j < 4; ++j) acc[i][j] = (f32x4)(0.f);
  bhalf8 a0[4][2], a1[4][2], b0[2][2], b1[2][2];

  // prologue: tile0 -> buf0 (8 loads), tile1 -> buf1 (8 loads)
  STAGE_A(0, 0, 0);   STAGE_A(0, 1, 0);
  STAGE_B(0, 0, 0);   STAGE_B(0, 1, 0);
  STAGE_A(1, 0, 64);  STAGE_A(1, 1, 64);
  STAGE_B(1, 0, 64);  STAGE_B(1, 1, 64);
  asm volatile("s_waitcnt vmcnt(8)" ::: "memory");   // tile0 landed
  BAR();
  READ_A(a0, 0, 0);
  READ_B(b0, 0, 0);

  #pragma unroll 1
  for (int t2 = 0; t2 < 7; ++t2) {          // tiles t=0..13 (full pipeline)
    KT2(0, 1, 1, (2 * t2 + 2) * 64);
    KT2(1, 1, 1, (2 * t2 + 3) * 64);
  }
  KT2(0, 0, 1, 0);                           // t=14: no stage, read t=15 frags
  KT2(1, 0, 0, 0);                           // t=15: drain

  // ---------------- epilogue (two passes through LDS) ----------------
  const int LDM = 264;                        // shorts; 528B rows
  if (TRANSPOSED) {
    const int bl   = bm >> 2;                 // chunk-local batch
    const int ioff = (bm & 3) * 256;
    #pragma unroll 1
    for (int p = 0; p < 2; ++p) {
      __syncthreads();
      if ((wc >> 1) == p) {
        #pragma unroll
        for (int ni = 0; ni < 4; ++ni) {
          float bb = bias[bn * 256 + wc * 64 + ni * 16 + (lane & 15)];
          int n128 = (wc & 1) * 64 + ni * 16 + (lane & 15);
          #pragma unroll
          for (int mi = 0; mi < 8; ++mi) {
            int mloc = wr * 128 + mi * 16 + kq * 4;
            bhalf4 pk;
            #pragma unroll
            for (int e = 0; e < 4; ++e) pk[e] = f2bf(acc[mi][ni][e] + bb);
            *(bhalf4*)(smem + n128 * LDM + mloc) = pk;
          }
        }
      }
      __syncthreads();
      #pragma unroll
      for (int r = 0; r < 4; ++r) {
        int row = r * 32 + (t >> 4);
        int ck  = (t & 15) * 16;
        bhalf8 v0 = *(const bhalf8*)(smem + row * LDM + ck);
        bhalf8 v1 = *(const bhalf8*)(smem + row * LDM + ck + 8);
        size_t dst = ((size_t)bl * HD + (bn * 256 + p * 128 + row)) * 1024 + ioff + ck;
        *(bhalf8*)(C + dst) = v0;
        *(bhalf8*)(C + dst + 8) = v1;
      }
    }
  } else {
    #pragma unroll 1
    for (int p = 0; p < 2; ++p) {
      __syncthreads();
      if (wr == p) {
        #pragma unroll
        for (int ni = 0; ni < 4; ++ni) {
          float bb = bias[bn * 256 + wc * 64 + ni * 16 + (lane & 15)];
          int nloc = wc * 64 + ni * 16 + (lane & 15);
          #pragma unroll
          for (int mi = 0; mi < 8; ++mi) {
            int mloc = mi * 16 + kq * 4;
            #pragma unroll
            for (int e = 0; e < 4; ++e)
              smem[(mloc + e) * LDM + nloc] = f2bf(acc[mi][ni][e] + bb);
          }
        }
      }
      __syncthreads();
      #pragma unroll
      for (int r = 0; r < 4; ++r) {
        int row = r * 32 + (t >> 4);
        int ck  = (t & 15) * 16;
        bhalf8 v0 = *(const bhalf8*)(smem + row * LDM + ck);
        bhalf8 v1 = *(const bhalf8*)(smem + row * LDM + ck + 8);
        size_t dst = (size_t)(bm * 256 + p * 128 + row) * HD + bn * 256 + ck;
        *(bhalf8*)(C + dst) = v0;
        *(bhalf8*)(C + dst + 8) = v1;
      }
    }
  }
}

// ---------- 3b) fallback 128^2 GEMM (verified) for tiny-ws tiers ----------
template <bool TRANSPOSED>
__global__ __launch_bounds__(256, 2)
void gemm_proj(const short* __restrict__ A, const short* __restrict__ BT,
               const float* __restrict__ bias, short* __restrict__ C) {
  constexpr int LDC = 136;
  __shared__ alignas(16) short smem2[128 * LDC];
  short* As = smem2;
  short* Bs = smem2 + 8192;
  short* Cs = smem2;

  const int t    = threadIdx.x;
  const int lane = t & 63;
  const int wave = t >> 6;
  const int bm   = blockIdx.x >> 6;
  const int bn   = blockIdx.x & 63;
  const int wr   = wave >> 1, wc = wave & 1;

  f32x4 acc[4][4];
  #pragma unroll
  for (int i = 0; i < 4; ++i)
    #pragma unroll
    for (int j = 0; j < 4; ++j) acc[i][j] = (f32x4)(0.f);

  const int gslot = ((lane & 7) ^ (lane >> 3)) * 8;
  const short* aRow = A  + (size_t)(bm * 128 + (lane >> 3)) * KDIM + gslot;
  const short* bRow = BT + (size_t)(bn * 128 + (lane >> 3)) * KDIM + gslot;

  const int arow = wr * 64 + (lane & 15);
  const int brow = wc * 64 + (lane & 15);
  const int kbase = (lane >> 4) * 8;
  const int swz  = (lane & 7) * 8;

  for (int kt = 0; kt < 16; ++kt) {
    __syncthreads();
    #pragma unroll
    for (int s = 0; s < 4; ++s) {
      int c = s * 4 + wave;
      __builtin_amdgcn_global_load_lds(
          (glb_void*)(aRow + (size_t)(c * 8) * KDIM + kt * 64),
          (lds_void*)((char*)As + c * 1024), 16, 0, 0);
      __builtin_amdgcn_global_load_lds(
          (glb_void*)(bRow + (size_t)(c * 8) * KDIM + kt * 64),
          (lds_void*)((char*)Bs + c * 1024), 16, 0, 0);
    }
    __syncthreads();
    #pragma unroll
    for (int kk = 0; kk < 2; ++kk) {
      bhalf8 af[4], bfm[4];
      #pragma unroll
      for (int mi = 0; mi < 4; ++mi)
        af[mi] = *(const bhalf8*)(As + (arow + mi * 16) * 64 + ((kk * 32 + kbase) ^ swz));
      #pragma unroll
      for (int ni = 0; ni < 4; ++ni)
        bfm[ni] = *(const bhalf8*)(Bs + (brow + ni * 16) * 64 + ((kk * 32 + kbase) ^ swz));
      #pragma unroll
      for (int mi = 0; mi < 4; ++mi)
        #pragma unroll
        for (int ni = 0; ni < 4; ++ni)
          acc[mi][ni] = __builtin_amdgcn_mfma_f32_16x16x32_bf16(af[mi], bfm[ni], acc[mi][ni], 0, 0, 0);
    }
  }

  __syncthreads();

  float bv4[4];
  #pragma unroll
  for (int ni = 0; ni < 4; ++ni) bv4[ni] = bias[bn * 128 + wc * 64 + ni * 16 + (lane & 15)];

  #pragma unroll
  for (int mi = 0; mi < 4; ++mi) {
    #pragma unroll
    for (int ni = 0; ni < 4; ++ni) {
      const int r0 = wr * 64 + mi * 16 + (lane >> 4) * 4;
      const int cl = wc * 64 + ni * 16 + (lane & 15);
      if (TRANSPOSED) {
        bhalf4 pk;
        #pragma unroll
        for (int e = 0; e < 4; ++e) pk[e] = f2bf(acc[mi][ni][e] + bv4[ni]);
        *(bhalf4*)(Cs + cl * LDC + r0) = pk;
      } else {
        #pragma unroll
        for (int e = 0; e < 4; ++e) Cs[(r0 + e) * LDC + cl] = f2bf(acc[mi][ni][e] + bv4[ni]);
      }
    }
  }
  __syncthreads();

  #pragma unroll
  for (int p = 0; p < 8; ++p) {
    const int row = p * 16 + (t >> 4);
    const int ck  = (t & 15) * 8;
    bhalf8 v = *(const bhalf8*)(Cs + row * LDC + ck);
    if (TRANSPOSED) {
      const int n_g   = bn * 128 + row;
      const int mbase = bm * 128;
      const int bl    = mbase >> 10;
      const int ib    = (mbase & 1023) + ck;
      *(bhalf8*)(C + ((size_t)bl * HD + n_g) * 1024 + ib) = v;
    } else {
      const int m_g = bm * 128 + row;
      *(bhalf8*)(C + (size_t)m_g * HD + bn * 128 + ck) = v;
    }
  }
}

// ---------- 4) fused kv / softmax(axis=i) / pooled ----------
__global__ __launch_bounds__(256)
void pool_softmax(const short* __restrict__ QT, const short* __restrict__ KT,
                  const short* __restrict__ V, float* __restrict__ pooled, int b0) {
  const int t    = threadIdx.x;
  const int lane = t & 63;
  const int wave = t >> 6;
  const int task = blockIdx.x * 4 + wave;
  const int j  = task & 1023;
  const int bh = task >> 10;
  const int bl = bh >> 3, h = bh & 7;
  const size_t n = (size_t)h * 1024 + j;

  const bhalf8* qp = (const bhalf8*)(QT + ((size_t)bl * HD + n) * 1024);
  const bhalf8* kp = (const bhalf8*)(KT + ((size_t)bl * HD + n) * 1024);
  const bhalf8* vp = (const bhalf8*)(V + ((size_t)bl * 1024 + j) * HD + (size_t)h * 1024);

  bhalf8 q0 = qp[lane], q1 = qp[64 + lane];
  bhalf8 k0 = kp[lane], k1 = kp[64 + lane];
  bhalf8 v0 = vp[lane], v1 = vp[64 + lane];

  float q[16], x[16];
  float m = -1e30f;
  #pragma unroll
  for (int e = 0; e < 8; ++e) {
    q[e]     = bf2f(q0[e]);  q[8 + e] = bf2f(q1[e]);
    x[e]     = bf2f(k0[e]) * bf2f(v0[e]) * 0.03125f;
    x[8 + e] = bf2f(k1[e]) * bf2f(v1[e]) * 0.03125f;
  }
  #pragma unroll
  for (int e = 0; e < 16; ++e) m = fmaxf(m, x[e]);
  #pragma unroll
  for (int off = 32; off; off >>= 1) m = fmaxf(m, __shfl_xor(m, off, 64));
  float se = 0.f, sq = 0.f;
  #pragma unroll
  for (int e = 0; e < 16; ++e) { float ex = __expf(x[e] - m); se += ex; sq += ex * q[e]; }
  #pragma unroll
  for (int off = 32; off; off >>= 1) { se += __shfl_xor(se, off, 64); sq += __shfl_xor(sq, off, 64); }
  if (lane == 0) pooled[((size_t)(b0 * 8) + bh) * 1024 + j] = sq / se;
}

// ---------- 5) out = pooled @ WL + bL, k-split x4 + reduce ----------
__global__ __launch_bounds__(256)
void final_gemm2(const float* __restrict__ pooled, const float* __restrict__ WL,
                 float* __restrict__ part) {
  __shared__ float sp[256][8];
  const int t  = threadIdx.x;
  const int bn = blockIdx.x;   // 32
  const int mg = blockIdx.y;   // 8
  const int kc = blockIdx.z;   // 4
  for (int idx = t; idx < 2048; idx += 256) {
    int mm = idx >> 8, k = idx & 255;
    sp[k][mm] = pooled[(size_t)(mg * 8 + mm) * 1024 + kc * 256 + k];
  }
  __syncthreads();
  const int n = bn * 256 + t;
  float acc[8];
  #pragma unroll
  for (int mm = 0; mm < 8; ++mm) acc[mm] = 0.f;
  const float* wp = WL + (size_t)(kc * 256) * HD + n;
  #pragma unroll 1
  for (int k0 = 0; k0 < 256; k0 += 8) {
    float wv[8];
    #pragma unroll
    for (int u = 0; u < 8; ++u) wv[u] = wp[(size_t)(k0 + u) * HD];
    #pragma unroll
    for (int u = 0; u < 8; ++u)
      #pragma unroll
      for (int mm = 0; mm < 8; ++mm) acc[mm] = fmaf(sp[k0 + u][mm], wv[u], acc[mm]);
  }
  #pragma unroll
  for (int mm = 0; mm < 8; ++mm)
    part[((size_t)kc * 64 + mg * 8 + mm) * HD + n] = acc[mm];
}

__global__ __launch_bounds__(256)
void final_reduce(const float* __restrict__ part, const float* __restrict__ bL,
                  float* __restrict__ out) {
  int id = blockIdx.x * 256 + threadIdx.x;        // 131072 f32x4 groups
  const f32x4* p4 = (const f32x4*)part;
  f32x4 s = p4[id];
  s = s + p4[131072 + id];
  s = s + p4[262144 + id];
  s = s + p4[393216 + id];
  f32x4 bb = ((const f32x4*)bL)[id & 2047];
  ((f32x4*)out)[id] = s + bb;
}

// ---------- launch ----------
extern "C" void kernel_launch(void* const* d_in, const int* in_sizes, int n_in,
                              void* d_out, int out_size, void* d_ws, size_t ws_size,
                              hipStream_t stream) {
  const float* inputs = (const float*)d_in[0];
  const float* Wq = (const float*)d_in[1];
  const float* bq = (const float*)d_in[2];
  const float* Wk = (const float*)d_in[3];
  const float* bk = (const float*)d_in[4];
  const float* Wv = (const float*)d_in[5];
  const float* bv = (const float*)d_in[6];
  const float* WL = (const float*)d_in[7];
  const float* bL = (const float*)d_in[8];
  float* out = (float*)d_out;

  const size_t MB = 1ull << 20;
  int CB; bool threeW;
  if      (ws_size >= 449 * MB) { CB = 8; threeW = true;  }
  else if (ws_size >= 249 * MB) { CB = 4; threeW = true;  }
  else if (ws_size >= 149 * MB) { CB = 2; threeW = true;  }
  else if (ws_size >=  99 * MB) { CB = 1; threeW = true;  }
  else                          { CB = 1; threeW = false; }

  char* ws = (char*)d_ws;
  short* WT0 = (short*)ws;
  short* WT1 = threeW ? (short*)(ws + 16 * MB) : WT0;
  short* WT2 = threeW ? (short*)(ws + 32 * MB) : WT0;
  char* pp = ws + (threeW ? 48 : 16) * MB;
  short* Abf = (short*)pp;  pp += (size_t)CB * 2  * MB;
  short* QT  = (short*)pp;  pp += (size_t)CB * 16 * MB;
  short* KT  = (short*)pp;  pp += (size_t)CB * 16 * MB;
  short* Vn  = (short*)pp;  pp += (size_t)CB * 16 * MB;
  float* pooled = (float*)pp;
  float* part = (float*)QT;      // 8 MB partials; QT free when final runs

  const float* Wmat[3] = {Wq, Wk, Wv};
  const float* bvec[3] = {bq, bk, bv};
  short*       WTs[3]  = {WT0, WT1, WT2};
  short*       Cout[3] = {QT, KT, Vn};
  const bool   big = (CB >= 2);

  dim3 tg(16, 128);
  if (threeW)
    for (int pj = 0; pj < 3; ++pj)
      transpose_w<<<tg, 256, 0, stream>>>(Wmat[pj], WTs[pj]);

  for (int b0 = 0; b0 < 8; b0 += CB) {
    cvt_f32_bf16<<<CB * 512, 256, 0, stream>>>(inputs + ((size_t)b0 << 20), Abf, CB << 17);
    for (int pj = 0; pj < 3; ++pj) {
      if (!threeW)
        transpose_w<<<tg, 256, 0, stream>>>(Wmat[pj], WT0);
      if (big) {
        if (pj < 2)
          gemm256<true ><<<CB * 128, 512, 0, stream>>>(Abf, WTs[pj], bvec[pj], Cout[pj]);
        else
          gemm256<false><<<CB * 128, 512, 0, stream>>>(Abf, WTs[pj], bvec[pj], Cout[pj]);
      } else {
        if (pj < 2)
          gemm_proj<true ><<<CB * 512, 256, 0, stream>>>(Abf, WTs[pj], bvec[pj], Cout[pj]);
        else
          gemm_proj<false><<<CB * 512, 256, 0, stream>>>(Abf, WTs[pj], bvec[pj], Cout[pj]);
      }
    }
    pool_softmax<<<CB * 2048, 256, 0, stream>>>(QT, KT, Vn, pooled, b0);
  }
  final_gemm2<<<dim3(32, 8, 4), 256, 0, stream>>>(pooled, WL, part);
  final_reduce<<<512, 256, 0, stream>>>(part, bL, out);
}

// Round 5
// 530.989 us; speedup vs baseline: 1.6251x; 1.6251x over previous
//
#include <hip/hip_runtime.h>
#include <hip/hip_bf16.h>
#include <stdint.h>

// ---------- types ----------
typedef __attribute__((ext_vector_type(4))) float  f32x4;
typedef __attribute__((ext_vector_type(4))) float  fvec4;
typedef __attribute__((ext_vector_type(8))) short  bhalf8;   // 8 bf16 (raw bits)
typedef __attribute__((ext_vector_type(4))) short  bhalf4;

typedef const __attribute__((address_space(1))) void glb_void;
typedef __attribute__((address_space(3))) void lds_void;

#define HD 8192
#define KDIM 1024

__device__ __forceinline__ float bf2f(short s) {
  union { float f; uint32_t u; } cv; cv.u = ((uint32_t)(uint16_t)s) << 16; return cv.f;
}
__device__ __forceinline__ short f2bf(float f) {
  union { float f; uint32_t u; } cv; cv.f = f;
  uint32_t u = cv.u;
  uint32_t r = (u + 0x7FFFu + ((u >> 16) & 1u)) >> 16;  // RNE
  return (short)(uint16_t)r;
}

// ---------- 1) f32 -> bf16 convert ----------
__global__ void cvt_f32_bf16(const float* __restrict__ in, short* __restrict__ out, int n8) {
  int idx = blockIdx.x * blockDim.x + threadIdx.x;
  if (idx >= n8) return;
  fvec4 a = ((const fvec4*)in)[idx * 2 + 0];
  fvec4 b = ((const fvec4*)in)[idx * 2 + 1];
  bhalf8 o;
  o[0]=f2bf(a[0]); o[1]=f2bf(a[1]); o[2]=f2bf(a[2]); o[3]=f2bf(a[3]);
  o[4]=f2bf(b[0]); o[5]=f2bf(b[1]); o[6]=f2bf(b[2]); o[7]=f2bf(b[3]);
  ((bhalf8*)out)[idx] = o;
}

// ---------- 2) W[1024][8192] f32 -> WT[8192][1024] bf16 ----------
__global__ __launch_bounds__(256)
void transpose_w(const float* __restrict__ W, short* __restrict__ WT) {
  __shared__ float tile[64][65];
  const int bk = blockIdx.x;   // 16
  const int bn = blockIdx.y;   // 128
  const int t  = threadIdx.x;
  #pragma unroll
  for (int p = 0; p < 4; ++p) {
    int r = p * 16 + (t >> 4);
    int c = (t & 15) * 4;
    fvec4 v = *(const fvec4*)(W + (size_t)(bk * 64 + r) * HD + bn * 64 + c);
    tile[r][c+0] = v[0]; tile[r][c+1] = v[1]; tile[r][c+2] = v[2]; tile[r][c+3] = v[3];
  }
  __syncthreads();
  #pragma unroll
  for (int p = 0; p < 2; ++p) {
    int rr = p * 32 + (t >> 3);
    int cc = (t & 7) * 8;
    bhalf8 o;
    #pragma unroll
    for (int e = 0; e < 8; ++e) o[e] = f2bf(tile[cc + e][rr]);
    *(bhalf8*)(WT + (size_t)(bn * 64 + rr) * KDIM + bk * 64 + cc) = o;
  }
}

// ---------- 3) 128x128 GEMM (verified best: ~1045 TF in R2 context) ----------
// A:[M][1024] bf16, BT:[8192][1024] bf16.
// TRANSPOSED: CT[b_l][n][i] (b_l = m/1024, i = m%1024); else C[m][8192].
template <bool TRANSPOSED>
__global__ __launch_bounds__(256, 2)
void gemm_proj(const short* __restrict__ A, const short* __restrict__ BT,
               const float* __restrict__ bias, short* __restrict__ C) {
  constexpr int LDC = 136;                 // bf16 elems; 272B row stride
  __shared__ alignas(16) short smem2[128 * LDC];   // 34816 B: As+Bs, then Cs
  short* As = smem2;
  short* Bs = smem2 + 8192;
  short* Cs = smem2;

  const int t    = threadIdx.x;
  const int lane = t & 63;
  const int wave = t >> 6;
  const int bm   = blockIdx.x >> 6;
  const int bn   = blockIdx.x & 63;
  const int wr   = wave >> 1, wc = wave & 1;

  f32x4 acc[4][4];
  #pragma unroll
  for (int i = 0; i < 4; ++i)
    #pragma unroll
    for (int j = 0; j < 4; ++j) acc[i][j] = (f32x4)(0.f);

  // staging: lane covers row (c*8 + lane>>3), LDS slot (lane&7); global slot
  // pre-swizzled: gslot = (lane&7) ^ (row&7)   [rule #21: linear LDS dest]
  const int gslot = ((lane & 7) ^ (lane >> 3)) * 8;
  const short* aRow = A  + (size_t)(bm * 128 + (lane >> 3)) * KDIM + gslot;
  const short* bRow = BT + (size_t)(bn * 128 + (lane >> 3)) * KDIM + gslot;

  const int arow = wr * 64 + (lane & 15);
  const int brow = wc * 64 + (lane & 15);
  const int kbase = (lane >> 4) * 8;       // pre-XOR k elem offset within row
  const int swz  = (lane & 7) * 8;         // read-side XOR (row&7 == lane&7)

  for (int kt = 0; kt < 16; ++kt) {
    __syncthreads();
    #pragma unroll
    for (int s = 0; s < 4; ++s) {
      int c = s * 4 + wave;
      __builtin_amdgcn_global_load_lds(
          (glb_void*)(aRow + (size_t)(c * 8) * KDIM + kt * 64),
          (lds_void*)((char*)As + c * 1024), 16, 0, 0);
      __builtin_amdgcn_global_load_lds(
          (glb_void*)(bRow + (size_t)(c * 8) * KDIM + kt * 64),
          (lds_void*)((char*)Bs + c * 1024), 16, 0, 0);
    }
    __syncthreads();
    #pragma unroll
    for (int kk = 0; kk < 2; ++kk) {
      bhalf8 af[4], bfm[4];
      #pragma unroll
      for (int mi = 0; mi < 4; ++mi)
        af[mi] = *(const bhalf8*)(As + (arow + mi * 16) * 64 + ((kk * 32 + kbase) ^ swz));
      #pragma unroll
      for (int ni = 0; ni < 4; ++ni)
        bfm[ni] = *(const bhalf8*)(Bs + (brow + ni * 16) * 64 + ((kk * 32 + kbase) ^ swz));
      #pragma unroll
      for (int mi = 0; mi < 4; ++mi)
        #pragma unroll
        for (int ni = 0; ni < 4; ++ni)
          acc[mi][ni] = __builtin_amdgcn_mfma_f32_16x16x32_bf16(af[mi], bfm[ni], acc[mi][ni], 0, 0, 0);
    }
  }

  __syncthreads();   // all frag reads done; reuse smem as Cs

  float bv4[4];
  #pragma unroll
  for (int ni = 0; ni < 4; ++ni) bv4[ni] = bias[bn * 128 + wc * 64 + ni * 16 + (lane & 15)];

  #pragma unroll
  for (int mi = 0; mi < 4; ++mi) {
    #pragma unroll
    for (int ni = 0; ni < 4; ++ni) {
      const int r0 = wr * 64 + mi * 16 + (lane >> 4) * 4;   // m_local
      const int cl = wc * 64 + ni * 16 + (lane & 15);       // n_local
      if (TRANSPOSED) {
        bhalf4 pk;
        #pragma unroll
        for (int e = 0; e < 4; ++e) pk[e] = f2bf(acc[mi][ni][e] + bv4[ni]);
        *(bhalf4*)(Cs + cl * LDC + r0) = pk;           // Cs[n_local][m_local]
      } else {
        #pragma unroll
        for (int e = 0; e < 4; ++e) Cs[(r0 + e) * LDC + cl] = f2bf(acc[mi][ni][e] + bv4[ni]);
      }
    }
  }
  __syncthreads();

  #pragma unroll
  for (int p = 0; p < 8; ++p) {
    const int row = p * 16 + (t >> 4);
    const int ck  = (t & 15) * 8;
    bhalf8 v = *(const bhalf8*)(Cs + row * LDC + ck);
    if (TRANSPOSED) {
      const int n_g   = bn * 128 + row;
      const int mbase = bm * 128;
      const int bl    = mbase >> 10;                  // chunk-local batch
      const int ib    = (mbase & 1023) + ck;
      *(bhalf8*)(C + ((size_t)bl * HD + n_g) * 1024 + ib) = v;
    } else {
      const int m_g = bm * 128 + row;
      *(bhalf8*)(C + (size_t)m_g * HD + bn * 128 + ck) = v;
    }
  }
}

// ---------- 4) fused kv / softmax(axis=i) / pooled, per chunk ----------
__global__ __launch_bounds__(256)
void pool_softmax(const short* __restrict__ QT, const short* __restrict__ KT,
                  const short* __restrict__ V, float* __restrict__ pooled, int b0) {
  const int t    = threadIdx.x;
  const int lane = t & 63;
  const int wave = t >> 6;
  const int task = blockIdx.x * 4 + wave;
  const int j  = task & 1023;
  const int bh = task >> 10;
  const int bl = bh >> 3, h = bh & 7;
  const size_t n = (size_t)h * 1024 + j;

  const bhalf8* qp = (const bhalf8*)(QT + ((size_t)bl * HD + n) * 1024);
  const bhalf8* kp = (const bhalf8*)(KT + ((size_t)bl * HD + n) * 1024);
  const bhalf8* vp = (const bhalf8*)(V + ((size_t)bl * 1024 + j) * HD + (size_t)h * 1024);

  bhalf8 q0 = qp[lane], q1 = qp[64 + lane];
  bhalf8 k0 = kp[lane], k1 = kp[64 + lane];
  bhalf8 v0 = vp[lane], v1 = vp[64 + lane];

  float q[16], x[16];
  float m = -1e30f;
  #pragma unroll
  for (int e = 0; e < 8; ++e) {
    q[e]     = bf2f(q0[e]);  q[8 + e] = bf2f(q1[e]);
    x[e]     = bf2f(k0[e]) * bf2f(v0[e]) * 0.03125f;
    x[8 + e] = bf2f(k1[e]) * bf2f(v1[e]) * 0.03125f;
  }
  #pragma unroll
  for (int e = 0; e < 16; ++e) m = fmaxf(m, x[e]);
  #pragma unroll
  for (int off = 32; off; off >>= 1) m = fmaxf(m, __shfl_xor(m, off, 64));
  float se = 0.f, sq = 0.f;
  #pragma unroll
  for (int e = 0; e < 16; ++e) { float ex = __expf(x[e] - m); se += ex; sq += ex * q[e]; }
  #pragma unroll
  for (int off = 32; off; off >>= 1) { se += __shfl_xor(se, off, 64); sq += __shfl_xor(sq, off, 64); }
  if (lane == 0) pooled[((size_t)(b0 * 8) + bh) * 1024 + j] = sq / se;
}

// ---------- 5) out = pooled @ WL + bL, k-split x4 + reduce ----------
__global__ __launch_bounds__(256)
void final_gemm2(const float* __restrict__ pooled, const float* __restrict__ WL,
                 float* __restrict__ part) {
  __shared__ float sp[256][8];
  const int t  = threadIdx.x;
  const int bn = blockIdx.x;   // 32
  const int mg = blockIdx.y;   // 8
  const int kc = blockIdx.z;   // 4
  for (int idx = t; idx < 2048; idx += 256) {
    int mm = idx >> 8, k = idx & 255;
    sp[k][mm] = pooled[(size_t)(mg * 8 + mm) * 1024 + kc * 256 + k];
  }
  __syncthreads();
  const int n = bn * 256 + t;
  float acc[8];
  #pragma unroll
  for (int mm = 0; mm < 8; ++mm) acc[mm] = 0.f;
  const float* wp = WL + (size_t)(kc * 256) * HD + n;
  #pragma unroll 1
  for (int k0 = 0; k0 < 256; k0 += 8) {
    float wv[8];
    #pragma unroll
    for (int u = 0; u < 8; ++u) wv[u] = wp[(size_t)(k0 + u) * HD];
    #pragma unroll
    for (int u = 0; u < 8; ++u)
      #pragma unroll
      for (int mm = 0; mm < 8; ++mm) acc[mm] = fmaf(sp[k0 + u][mm], wv[u], acc[mm]);
  }
  #pragma unroll
  for (int mm = 0; mm < 8; ++mm)
    part[((size_t)kc * 64 + mg * 8 + mm) * HD + n] = acc[mm];
}

__global__ __launch_bounds__(256)
void final_reduce(const float* __restrict__ part, const float* __restrict__ bL,
                  float* __restrict__ out) {
  int id = blockIdx.x * 256 + threadIdx.x;        // 131072 f32x4 groups
  const f32x4* p4 = (const f32x4*)part;
  f32x4 s = p4[id];
  s = s + p4[131072 + id];
  s = s + p4[262144 + id];
  s = s + p4[393216 + id];
  f32x4 bb = ((const f32x4*)bL)[id & 2047];
  ((f32x4*)out)[id] = s + bb;
}

// ---------- launch ----------
extern "C" void kernel_launch(void* const* d_in, const int* in_sizes, int n_in,
                              void* d_out, int out_size, void* d_ws, size_t ws_size,
                              hipStream_t stream) {
  const float* inputs = (const float*)d_in[0];
  const float* Wq = (const float*)d_in[1];
  const float* bq = (const float*)d_in[2];
  const float* Wk = (const float*)d_in[3];
  const float* bk = (const float*)d_in[4];
  const float* Wv = (const float*)d_in[5];
  const float* bv = (const float*)d_in[6];
  const float* WL = (const float*)d_in[7];
  const float* bL = (const float*)d_in[8];
  float* out = (float*)d_out;

  const size_t MB = 1ull << 20;
  int CB; bool threeW;
  if      (ws_size >= 449 * MB) { CB = 8; threeW = true;  }
  else if (ws_size >= 249 * MB) { CB = 4; threeW = true;  }
  else if (ws_size >= 149 * MB) { CB = 2; threeW = true;  }
  else if (ws_size >=  99 * MB) { CB = 1; threeW = true;  }
  else                          { CB = 1; threeW = false; }

  char* ws = (char*)d_ws;
  short* WT0 = (short*)ws;
  short* WT1 = threeW ? (short*)(ws + 16 * MB) : WT0;
  short* WT2 = threeW ? (short*)(ws + 32 * MB) : WT0;
  char* pp = ws + (threeW ? 48 : 16) * MB;
  short* Abf = (short*)pp;  pp += (size_t)CB * 2  * MB;
  short* QT  = (short*)pp;  pp += (size_t)CB * 16 * MB;
  short* KT  = (short*)pp;  pp += (size_t)CB * 16 * MB;
  short* Vn  = (short*)pp;  pp += (size_t)CB * 16 * MB;
  float* pooled = (float*)pp;
  float* part = (float*)QT;      // 8 MB partials; QT free when final runs

  const float* Wmat[3] = {Wq, Wk, Wv};
  const float* bvec[3] = {bq, bk, bv};
  short*       WTs[3]  = {WT0, WT1, WT2};
  short*       Cout[3] = {QT, KT, Vn};

  dim3 tg(16, 128);
  if (threeW)
    for (int pj = 0; pj < 3; ++pj)
      transpose_w<<<tg, 256, 0, stream>>>(Wmat[pj], WTs[pj]);

  for (int b0 = 0; b0 < 8; b0 += CB) {
    cvt_f32_bf16<<<CB * 512, 256, 0, stream>>>(inputs + ((size_t)b0 << 20), Abf, CB << 17);
    for (int pj = 0; pj < 3; ++pj) {
      if (!threeW)
        transpose_w<<<tg, 256, 0, stream>>>(Wmat[pj], WT0);
      if (pj < 2)
        gemm_proj<true ><<<CB * 512, 256, 0, stream>>>(Abf, WTs[pj], bvec[pj], Cout[pj]);
      else
        gemm_proj<false><<<CB * 512, 256, 0, stream>>>(Abf, WTs[pj], bvec[pj], Cout[pj]);
    }
    pool_softmax<<<CB * 2048, 256, 0, stream>>>(QT, KT, Vn, pooled, b0);
  }
  final_gemm2<<<dim3(32, 8, 4), 256, 0, stream>>>(pooled, WL, part);
  final_reduce<<<512, 256, 0, stream>>>(part, bL, out);
}